// Round 3
// baseline (70.356 us; speedup 1.0000x reference)
//
#include <hip/hip_runtime.h>

// FM second-order term via f16 MFMA, two-kernel structure:
//   prep (1 block): wt^T = (W*2^13) transposed -> fp16 [64][KP] into d_ws,
//                   zero-padded k in [200,232); s[f] = sum_e W[f,e]^2 -> d_ws.
//   main (512 blocks x 256): flat-copy wt^T + sf into LDS, stream X (float4,
//                   issued before first barrier), q-term fp32, MFMA y = x@W,
//                   out[b] = sum_e y^2 * 2^-26 - q.
// B=16384, F=200(K, padded 224 used / 232 stored), E=64.

constexpr int F  = 200;
constexpr int RB = 32;              // rows per block
constexpr int KP = 232;             // fp16 row stride (464 B: b128-aligned, 2-way-free banks)
constexpr float WSCALE = 8192.0f;   // 2^13 (exact)
constexpr float OSCALE = 1.0f / (WSCALE * WSCALE);  // 2^-26 (exact)
constexpr int WT_HALF8 = 64 * KP / 8;               // 1856 chunks of 16 B
constexpr size_t WS_WT_OFF = 1024;                  // wt^T at ws+1024; sf at ws+0

typedef _Float16 half8 __attribute__((ext_vector_type(8)));
typedef _Float16 half4 __attribute__((ext_vector_type(4)));
typedef float floatx4 __attribute__((ext_vector_type(4)));

__global__ __launch_bounds__(256)
void fm_prep(const float* __restrict__ W, void* __restrict__ ws)
{
    __shared__ alignas(16) _Float16 wt[64][KP];
    const int t = threadIdx.x;

    // zero whole wt (covers the k in [200,232) pad)
    half8 z = {};
    #pragma unroll
    for (int j = 0; j < 8; ++j) {
        int c = t + 256 * j;
        if (c < WT_HALF8) *(half8*)&wt[0][c * 8] = z;
    }
    __syncthreads();

    float* sf_out = (float*)ws;
    const floatx4* W4 = (const floatx4*)W;        // 3200 float4, [f][e]
    for (int j = 0; j < 13; ++j) {
        int i = t + 256 * j;
        if (i < 3200) {
            floatx4 w4 = W4[i];
            int f  = i >> 4;                      // 16 float4 per f-row
            int e0 = (i & 15) * 4;
            float ss = w4.x*w4.x + w4.y*w4.y + w4.z*w4.z + w4.w*w4.w;
            ss += __shfl_xor(ss, 1, 64);
            ss += __shfl_xor(ss, 2, 64);
            ss += __shfl_xor(ss, 4, 64);
            ss += __shfl_xor(ss, 8, 64);
            if ((t & 15) == 0) sf_out[f] = ss;    // s[f] straight to ws
            wt[e0 + 0][f] = (_Float16)(w4.x * WSCALE);
            wt[e0 + 1][f] = (_Float16)(w4.y * WSCALE);
            wt[e0 + 2][f] = (_Float16)(w4.z * WSCALE);
            wt[e0 + 3][f] = (_Float16)(w4.w * WSCALE);
        }
    }
    __syncthreads();

    // coalesced write-out of wt^T (flat, stride already KP)
    const half8* src = (const half8*)&wt[0][0];
    half8* dst = (half8*)((char*)ws + WS_WT_OFF);
    #pragma unroll
    for (int j = 0; j < 8; ++j) {
        int c = t + 256 * j;
        if (c < WT_HALF8) dst[c] = src[c];
    }
}

__global__ __launch_bounds__(256)
void fm_main(const float* __restrict__ X, const void* __restrict__ ws,
             float* __restrict__ out)
{
    __shared__ alignas(16) _Float16 xt[RB][KP];   // 14.8 KB
    __shared__ alignas(16) _Float16 wt[64][KP];   // 29.7 KB
    __shared__ alignas(16) float    sf[F];
    __shared__ alignas(16) float    res[RB];

    const int t    = threadIdx.x;
    const int lane = t & 63;
    const int rowBase = (int)blockIdx.x * RB;

    // ---- issue X loads first (7 float4 per thread, coalesced in octets) ----
    const int r = t >> 3, sub = t & 7;            // 8 threads per row
    const floatx4* Xr = (const floatx4*)(X + (size_t)(rowBase + r) * F);
    floatx4 xv[7];
    #pragma unroll
    for (int j = 0; j < 7; ++j) {
        int f4 = sub + 8 * j;                     // 50 float4 per row
        if (f4 < 50) xv[j] = Xr[f4];
        else { floatx4 zz = {}; xv[j] = zz; }
    }

    // ---- stage wt^T + sf from ws (flat, coalesced) + zero xt pad ----------
    {
        const half8* wsrc = (const half8*)((const char*)ws + WS_WT_OFF);
        half8* wdst = (half8*)&wt[0][0];
        #pragma unroll
        for (int j = 0; j < 7; ++j) wdst[t + 256 * j] = wsrc[t + 256 * j]; // 1792
        if (t < WT_HALF8 - 1792) wdst[1792 + t] = wsrc[1792 + t];          // 1856
        if (t < 50) ((floatx4*)sf)[t] = ((const floatx4*)ws)[t];
        half8 z = {};
        if (t < 128) *(half8*)&xt[t >> 2][200 + 8 * (t & 3)] = z;  // k pad [200,232)
    }
    __syncthreads();

    // ---- q-term (fp32) + x -> fp16 LDS ------------------------------------
    {
        float q = 0.f;
        #pragma unroll
        for (int j = 0; j < 7; ++j) {
            int f4 = sub + 8 * j;
            if (f4 < 50) {
                floatx4 x4 = xv[j];
                floatx4 s4 = *(const floatx4*)&sf[4 * f4];
                q += x4.x*x4.x*s4.x + x4.y*x4.y*s4.y + x4.z*x4.z*s4.z + x4.w*x4.w*s4.w;
                half4 h;
                h[0] = (_Float16)x4.x; h[1] = (_Float16)x4.y;
                h[2] = (_Float16)x4.z; h[3] = (_Float16)x4.w;
                *(half4*)&xt[r][4 * f4] = h;
            }
        }
        q += __shfl_xor(q, 1, 64);
        q += __shfl_xor(q, 2, 64);
        q += __shfl_xor(q, 4, 64);
        if (sub == 0) res[r] = -q;
    }
    __syncthreads();

    // ---- MFMA y' = xt @ wt^T, epilogue -------------------------------------
    {
        const int w  = t >> 6;
        const int mt = (w & 1) * 16;              // row tile (0/16)
        const int nb = (w >> 1) * 32;             // e half (0/32)
        const int lm = lane & 15, lq = lane >> 4;

        const half8* ap  = (const half8*)&xt[mt + lm][lq * 8];
        const half8* b0p = (const half8*)&wt[nb + lm][lq * 8];
        const half8* b1p = (const half8*)&wt[nb + 16 + lm][lq * 8];

        floatx4 acc0 = {}, acc1 = {};
        #pragma unroll
        for (int kk = 0; kk < 7; ++kk) {          // K = 7*32 = 224
            half8 a  = ap [kk * 4];
            half8 b0 = b0p[kk * 4];
            half8 b1 = b1p[kk * 4];
            acc0 = __builtin_amdgcn_mfma_f32_16x16x32_f16(a, b0, acc0, 0, 0, 0);
            acc1 = __builtin_amdgcn_mfma_f32_16x16x32_f16(a, b1, acc1, 0, 0, 0);
        }

        float p[4];
        #pragma unroll
        for (int r2 = 0; r2 < 4; ++r2)
            p[r2] = acc0[r2]*acc0[r2] + acc1[r2]*acc1[r2];
        #pragma unroll
        for (int r2 = 0; r2 < 4; ++r2) {          // sum over 16 cols (lm)
            p[r2] += __shfl_xor(p[r2], 1, 64);
            p[r2] += __shfl_xor(p[r2], 2, 64);
            p[r2] += __shfl_xor(p[r2], 4, 64);
            p[r2] += __shfl_xor(p[r2], 8, 64);
        }
        if (lm == 0) {
            #pragma unroll
            for (int r2 = 0; r2 < 4; ++r2)
                atomicAdd(&res[mt + lq * 4 + r2], p[r2] * OSCALE);
        }
    }
    __syncthreads();

    if (t < RB) out[rowBase + t] = res[t];
}

extern "C" void kernel_launch(void* const* d_in, const int* in_sizes, int n_in,
                              void* d_out, int out_size, void* d_ws, size_t ws_size,
                              hipStream_t stream) {
    const float* X = (const float*)d_in[0];   // [16384, 200] fp32
    const float* W = (const float*)d_in[1];   // [200, 64] fp32
    float* out = (float*)d_out;               // [16384, 1] fp32

    const int B = in_sizes[0] / F;            // 16384
    fm_prep<<<1, 256, 0, stream>>>(W, d_ws);
    fm_main<<<B / RB, 256, 0, stream>>>(X, d_ws, out);
}